// Round 1
// baseline (313.786 us; speedup 1.0000x reference)
//
#include <hip/hip_runtime.h>

// Problem: B=4, S=2048, D=1024, H=16, HD=64.
#define NB 4
#define NS 2048
#define ND 1024
#define NH 16
#define NE 64
#define NM (NB*NS)   // 8192 rows

typedef __attribute__((ext_vector_type(8))) __bf16 bf16x8;           // MFMA A/B frag (4 VGPRs)
typedef __attribute__((ext_vector_type(4))) float f32x4;             // MFMA C/D frag

__device__ __forceinline__ float bf2f(unsigned short h) {
  union { unsigned u; float f; } c; c.u = ((unsigned)h) << 16; return c.f;
}
__device__ __forceinline__ unsigned short f2bf(float f) {
  union { float f; unsigned u; } c; c.f = f;
  return (unsigned short)((c.u + 0x7fffu + ((c.u >> 16) & 1u)) >> 16);
}
__device__ __forceinline__ void load16_to_lds(const void* g, void* l) {
  __builtin_amdgcn_global_load_lds(
      (__attribute__((address_space(1))) void*)(void*)(unsigned long long)(const char*)g,
      (__attribute__((address_space(3))) void*)l, 16, 0, 0);
}

// ---------- dtype detection: is d_in data bf16 (1) or fp32 (0)? ----------
__global__ void detect_dtype(const unsigned* __restrict__ x, int* __restrict__ flag) {
  __shared__ int cnt;
  if (threadIdx.x == 0) cnt = 0;
  __syncthreads();
  unsigned w = x[((unsigned)threadIdx.x * 16381u) & ((1u << 21) - 1u)];
  unsigned lo = w & 0xFFFFu;
  int e = (int)((lo >> 7) & 0xFF);
  int plausible = (lo == 0u) || (e >= 100 && e <= 142);
  atomicAdd(&cnt, plausible);
  __syncthreads();
  if (threadIdx.x == 0) *flag = (cnt >= 192) ? 1 : 0;
}

// ---------- canonicalize any input to bf16 ----------
__global__ void conv_to_bf16(const void* __restrict__ src, unsigned short* __restrict__ dst,
                             int n, const int* __restrict__ flag) {
  int stride = gridDim.x * blockDim.x;
  int i0 = blockIdx.x * blockDim.x + threadIdx.x;
  if (*flag) {
    const unsigned short* s = (const unsigned short*)src;
    for (int i = i0; i < n; i += stride) dst[i] = s[i];
  } else {
    const float* s = (const float*)src;
    for (int i = i0; i < n; i += stride) dst[i] = f2bf(s[i]);
  }
}

// ---------- fused convert+transpose: in[K][N] (bf16 or fp32 per flag) -> out[N][K] bf16 ----------
__global__ __launch_bounds__(256) void transpose_conv(const void* __restrict__ in,
                                                      unsigned short* __restrict__ out,
                                                      int K, int N, const int* __restrict__ flag) {
  __shared__ unsigned short tile[32][33];
  int n0 = blockIdx.x * 32, k0 = blockIdx.y * 32;
  int tx = threadIdx.x, ty = threadIdx.y;   // (32,8)
  if (*flag) {
    const unsigned short* p = (const unsigned short*)in;
#pragma unroll
    for (int i = 0; i < 4; ++i)
      tile[ty + 8*i][tx] = p[(size_t)(k0 + ty + 8*i) * N + n0 + tx];
  } else {
    const float* p = (const float*)in;
#pragma unroll
    for (int i = 0; i < 4; ++i)
      tile[ty + 8*i][tx] = f2bf(p[(size_t)(k0 + ty + 8*i) * N + n0 + tx]);
  }
  __syncthreads();
#pragma unroll
  for (int i = 0; i < 4; ++i)
    out[(size_t)(n0 + ty + 8*i) * K + k0 + tx] = tile[tx][ty + 8*i];
}

// ---------- m97-style GEMM core: C[128x128] = A[M,K] * Bt[N,K]^T (kept for gemm_proj) ----------
__device__ __forceinline__ void gemm_core(const unsigned short* __restrict__ A,
                                          const unsigned short* __restrict__ Bt,
                                          int K, int m0, int n0,
                                          unsigned short* As, unsigned short* Bs,
                                          f32x4 (&acc)[4][4]) {
  int t = threadIdx.x;
  int lane = t & 63;
  int w = t >> 6, wr = w >> 1, wc = w & 1;
  int frm = lane & 15, fko = (lane >> 4) * 8;
  for (int kk = 0; kk < K; kk += 32) {
#pragma unroll
    for (int c = 0; c < 2; ++c) {
      int L = c * 256 + t;
      int r = L >> 2, ko = (L & 3) * 8;
      load16_to_lds(A  + (size_t)(m0 + r) * K + kk + ko, (char*)As + L * 16);
      load16_to_lds(Bt + (size_t)(n0 + r) * K + kk + ko, (char*)Bs + L * 16);
    }
    __syncthreads();
    bf16x8 a[4], b[4];
#pragma unroll
    for (int i = 0; i < 4; ++i) a[i] = *(const bf16x8*)(As + (64*wr + 16*i + frm) * 32 + fko);
#pragma unroll
    for (int j = 0; j < 4; ++j) b[j] = *(const bf16x8*)(Bs + (64*wc + 16*j + frm) * 32 + fko);
#pragma unroll
    for (int i = 0; i < 4; ++i)
#pragma unroll
      for (int j = 0; j < 4; ++j)
        acc[i][j] = __builtin_amdgcn_mfma_f32_16x16x32_bf16(a[i], b[j], acc[i][j], 0, 0, 0);
    __syncthreads();
  }
}

// ---------- QKV projection: 256x256 tile, 8 waves, 4-deep LDS pipeline ----------
// Per K-tile (BK=32): 2 phases of {ds_read frags | stage 2 loads of tile t+3 | barrier |
// setprio(1) 16 MFMA setprio(0) | barrier}. One counted vmcnt(8) per K-tile keeps the
// 8 newest loads (tiles t+2,t+3) in flight across the barrier — never drains in steady state.
// LDS: 4 bufs x (A 256x32 + B 256x32) bf16 = 128 KiB, 1 block/CU, 8 waves.
// XOR chunk swizzle (c ^= (row>>1)&3) applied on the GLOBAL SOURCE in the stage and on the
// ds_read offset (both-sides, rule 21) -> 8-way bank conflict becomes 2-way (free).
#define TILE_ELEMS (256*32)

__global__ __launch_bounds__(512, 2) void gemm_qkv256(const unsigned short* __restrict__ X,
                                                      const unsigned short* __restrict__ W1T,
                                                      const unsigned short* __restrict__ battn,
                                                      unsigned short* __restrict__ qb,
                                                      unsigned short* __restrict__ kb,
                                                      unsigned short* __restrict__ vb) {
  __shared__ unsigned short sm[4 * 2 * TILE_ELEMS];   // 128 KiB
  const int t = threadIdx.x;                          // 0..511
  const int lane = t & 63, w = t >> 6;
  const int wr = w >> 2, wc = w & 3;                  // wave tile: 128(M) x 64(N)
  const int frm = lane & 15;
  const int gs = (lane >> 4) ^ ((frm >> 1) & 3);      // swizzled K-chunk for ds_read
  const int m0 = blockIdx.y * 256, n0 = blockIdx.x * 256;
  const int NT = ND / 32;                             // 32 K-tiles

  auto stage = [&](const unsigned short* __restrict__ src, int row0, int kk,
                   unsigned short* dstbase) {
#pragma unroll
    for (int i = 0; i < 2; ++i) {
      int ci = i * 512 + t;                 // 16B chunk id, lane-linear per wave
      int r = ci >> 2, c = ci & 3;
      int cs = c ^ ((r >> 1) & 3);          // inverse-swizzled global source
      load16_to_lds(src + (size_t)(row0 + r) * ND + kk + cs * 8,
                    (char*)dstbase + ci * 16);
    }
  };

  // prologue: stage tiles 0,1,2 (12 loads/thread); wait tile 0 (8 newest stay in flight)
#pragma unroll
  for (int u = 0; u < 3; ++u) {
    unsigned short* Ab = sm + u * (2 * TILE_ELEMS);
    stage(X,   m0, u * 32, Ab);
    stage(W1T, n0, u * 32, Ab + TILE_ELEMS);
  }
  asm volatile("s_waitcnt vmcnt(8)\n\ts_barrier" ::: "memory");

  f32x4 acc[8][4] = {};
  for (int kt = 0; kt < NT; ++kt) {
    unsigned short* Ab = sm + (kt & 3) * (2 * TILE_ELEMS);
    unsigned short* Bb = Ab + TILE_ELEMS;
    unsigned short* Sb = sm + ((kt + 3) & 3) * (2 * TILE_ELEMS);
    const bool st = (kt + 3 < NT);
    const int kk = (kt + 3) * 32;

    // ---- phase 0: B frags + A frags 0..3, stage A(t+3) ----
    bf16x8 b[4], a0[4];
#pragma unroll
    for (int j = 0; j < 4; ++j)
      b[j] = *(const bf16x8*)(Bb + (64*wc + 16*j + frm) * 32 + gs * 8);
#pragma unroll
    for (int i = 0; i < 4; ++i)
      a0[i] = *(const bf16x8*)(Ab + (128*wr + 16*i + frm) * 32 + gs * 8);
    if (st) stage(X, m0, kk, Sb);
    asm volatile("s_barrier" ::: "memory");
    __builtin_amdgcn_s_setprio(1);
#pragma unroll
    for (int i = 0; i < 4; ++i)
#pragma unroll
      for (int j = 0; j < 4; ++j)
        acc[i][j] = __builtin_amdgcn_mfma_f32_16x16x32_bf16(a0[i], b[j], acc[i][j], 0, 0, 0);
    __builtin_amdgcn_s_setprio(0);
    asm volatile("s_barrier" ::: "memory");

    // ---- phase 1: A frags 4..7 (B reused in regs), stage B(t+3) ----
    bf16x8 a1[4];
#pragma unroll
    for (int i = 0; i < 4; ++i)
      a1[i] = *(const bf16x8*)(Ab + (128*wr + 64 + 16*i + frm) * 32 + gs * 8);
    if (st) stage(W1T, n0, kk, Sb + TILE_ELEMS);
    asm volatile("s_barrier" ::: "memory");
    __builtin_amdgcn_s_setprio(1);
#pragma unroll
    for (int i = 0; i < 4; ++i)
#pragma unroll
      for (int j = 0; j < 4; ++j)
        acc[4+i][j] = __builtin_amdgcn_mfma_f32_16x16x32_bf16(a1[i], b[j], acc[4+i][j], 0, 0, 0);
    __builtin_amdgcn_s_setprio(0);
    // tile boundary: ensure tile kt+1 landed; keep stages of kt+2,kt+3 in flight
    if (kt < NT - 3)       asm volatile("s_waitcnt vmcnt(8)\n\ts_barrier" ::: "memory");
    else if (kt == NT - 3) asm volatile("s_waitcnt vmcnt(4)\n\ts_barrier" ::: "memory");
    else if (kt == NT - 2) asm volatile("s_waitcnt vmcnt(0)\n\ts_barrier" ::: "memory");
    // kt == NT-1: no further LDS consumers; fall through to epilogue
  }

  // epilogue: scatter q/k:(B,H,S,E), v:(B,H,E,S) — same mapping as verified 128² kernel
  const int coln = frm, rbase = (lane >> 4) * 4;
#pragma unroll
  for (int j = 0; j < 4; ++j) {
    int nn = n0 + 64*wc + 16*j + coln;       // 0..3071
    int qq = nn >> 10;                       // 0=q 1=k 2=v
    int h  = (nn >> 6) & 15;
    int e  = nn & 63;
    float bias = bf2f(battn[nn]);
    unsigned short* dst = (qq == 0) ? qb : ((qq == 1) ? kb : vb);
    float scale = (qq == 0) ? (0.125f * 1.44269504f) : 1.0f;
#pragma unroll
    for (int i = 0; i < 8; ++i) {
#pragma unroll
      for (int rr = 0; rr < 4; ++rr) {
        int mm = m0 + 128*wr + 16*i + rbase + rr;
        int bb = mm >> 11, s = mm & 2047;
        float v = (acc[i][j][rr] + bias) * scale;
        size_t idx;
        if (qq == 2) idx = (((size_t)bb * NH + h) * NE + e) * NS + s;   // V transposed
        else         idx = (((size_t)bb * NH + h) * NS + s) * NE + e;
        dst[idx] = f2bf(v);
      }
    }
  }
}

// ---------- causal flash attention: 1024 fully-resident blocks, 4/CU ----------
// Block i -> (bh = i&63, qt = QTAB[(i>>6)&3][i>>8]); QTAB rows sum to 30 so the 4
// co-resident blocks per CU (i, i+256, ...) balance AND share bh (K/V L2 locality).
// 128 q-rows/block (wave w owns rows 32w..32w+31), 32-key tiles, dbuf DMA, vmcnt(2).
// LDS 32 KB: QPs 16K (Q then P, pitch-64hw octet-swizzled) + K dbuf 8K + V dbuf 8K.
// Vt layout: 32 rows x 128B; row r = e-pair (2r, 2r+1) x 32 keys, octet-swizzled.
__global__ __launch_bounds__(256, 4) void attn_causal(const unsigned short* __restrict__ qb,
                                                      const unsigned short* __restrict__ kb,
                                                      const unsigned short* __restrict__ vtb,
                                                      unsigned short* __restrict__ ob) {
  __shared__ unsigned short QPs[128 * 64];
  __shared__ unsigned short Ks[2][32 * 64];
  __shared__ unsigned short Vt[2][32 * 64];

  int t = threadIdx.x, lane = t & 63, w = t >> 6;
  int qd = lane >> 4, li = lane & 15;
  int sw0 = ((qd ^ (li & 7)) * 8);
  int sw1 = (((4 + qd) ^ (li & 7)) * 8);

  const int qtab[4][4] = {{15,8,7,0},{14,9,6,1},{13,10,5,2},{12,11,4,3}};
  int bi = blockIdx.x;
  int bh = bi & 63;
  int qt = qtab[(bi >> 6) & 3][bi >> 8];
  int q0 = qt * 128;
  int NT = 4 * qt + 4;                       // number of 32-key tiles
  size_t base = (size_t)bh * NS * NE;
  int bb = bh >> 4, hh = bh & 15;

  bf16x8 onesf;
#pragma unroll
  for (int j = 0; j < 8; ++j) onesf[j] = (__bf16)1.0f;

  auto stage_kv = [&](int kt, int buf) {
    int k0 = kt * 32;
    int r = t >> 3, p = t & 7, l = p ^ (r & 7);
    load16_to_lds(kb + base + (size_t)(k0 + r) * NE + l * 8, (char*)Ks[buf] + t * 16);
    int e = 2 * r + (l >> 2);
    load16_to_lds(vtb + base + (size_t)e * NS + k0 + (l & 3) * 8, (char*)Vt[buf] + t * 16);
  };

  // stage Q (128x64, swizzled) + first K/V tile
#pragma unroll
  for (int c = 0; c < 4; ++c) {
    int ch = c * 256 + t;
    int r = ch >> 3, jl = (ch & 7) ^ (r & 7);
    load16_to_lds(qb + base + (size_t)(q0 + r) * NE + jl * 8, (char*)QPs + ch * 16);
  }
  stage_kv(0, 0);
  asm volatile("s_waitcnt vmcnt(2)\n\ts_barrier" ::: "memory");  // Q drained, kv0 in flight

  bf16x8 qa[2][2];
#pragma unroll
  for (int i = 0; i < 2; ++i) {
    const unsigned short* qr = QPs + (32*w + 16*i + li) * 64;
    qa[i][0] = *(const bf16x8*)(qr + sw0);
    qa[i][1] = *(const bf16x8*)(qr + sw1);
  }

  f32x4 o[2][4] = {};
  float l_run[2][4] = {};

  for (int kt = 0; kt < NT; ++kt) {
    int cur = kt & 1;
    // all waves done with buf[cur^1] (and, at kt=0, with their qa reads)
    asm volatile("s_waitcnt lgkmcnt(0)\n\ts_barrier" ::: "memory");
    if (kt + 1 < NT) {
      stage_kv(kt + 1, cur ^ 1);
      asm volatile("s_waitcnt vmcnt(2)\n\ts_barrier" ::: "memory");  // drain tile kt only
    } else {
      asm volatile("s_waitcnt vmcnt(0)\n\ts_barrier" ::: "memory");
    }

    int k0 = kt * 32;
    const unsigned short* Ksc = Ks[cur];
    const unsigned short* Vtc = Vt[cur];

    bf16x8 kfr[2][2];
#pragma unroll
    for (int c = 0; c < 2; ++c) {
      const unsigned short* kr = Ksc + (16*c + li) * 64;
      kfr[c][0] = *(const bf16x8*)(kr + sw0);
      kfr[c][1] = *(const bf16x8*)(kr + sw1);
    }

    int need_mask = (k0 >= q0);
#pragma unroll
    for (int i = 0; i < 2; ++i) {
#pragma unroll
      for (int c = 0; c < 2; ++c) {
        f32x4 s = {};
        s = __builtin_amdgcn_mfma_f32_16x16x32_bf16(qa[i][0], kfr[c][0], s, 0, 0, 0);
        s = __builtin_amdgcn_mfma_f32_16x16x32_bf16(qa[i][1], kfr[c][1], s, 0, 0, 0);
#pragma unroll
        for (int rr = 0; rr < 4; ++rr) {
          float pv = exp2f(s[rr]);
          if (need_mask) {
            int colk = k0 + 16*c + li;
            int rowq = q0 + 32*w + 16*i + qd*4 + rr;
            if (colk > rowq) pv = 0.f;
          }
          int prow = 32*w + 16*i + qd*4 + rr;
          int lo = 2*c + (li >> 3);
          QPs[prow * 64 + ((lo ^ (prow & 7)) * 8) + (li & 7)] =
              (unsigned short)(__float_as_uint(pv) >> 16);
        }
      }
    }

    // read P as A-operand (wave-local rows; in-order LDS => no barrier)
    bf16x8 pa[2];
#pragma unroll
    for (int i = 0; i < 2; ++i)
      pa[i] = *(const bf16x8*)(QPs + (32*w + 16*i + li) * 64 + sw0);

    // row sums via ones-MFMA (k=32 covers the whole tile)
#pragma unroll
    for (int i = 0; i < 2; ++i) {
      f32x4 sm = {};
      sm = __builtin_amdgcn_mfma_f32_16x16x32_bf16(pa[i], onesf, sm, 0, 0, 0);
#pragma unroll
      for (int rr = 0; rr < 4; ++rr) l_run[i][rr] += sm[rr];
    }

    // O += P V : B-frag from packed Vt (row = e>>1, octet = (e&1)*4+qd, swizzled)
#pragma unroll
    for (int c2 = 0; c2 < 4; ++c2) {
      const unsigned short* vr = Vtc + (8*c2 + (li >> 1)) * 64;
      bf16x8 vf = *(const bf16x8*)(vr + ((((li & 1) * 4 + qd) ^ ((li >> 1) & 7)) * 8));
#pragma unroll
      for (int i = 0; i < 2; ++i)
        o[i][c2] = __builtin_amdgcn_mfma_f32_16x16x32_bf16(pa[i], vf, o[i][c2], 0, 0, 0);
    }
  }

  // write O to (B,S,H,E)
#pragma unroll
  for (int i = 0; i < 2; ++i)
#pragma unroll
    for (int c = 0; c < 4; ++c)
#pragma unroll
      for (int rr = 0; rr < 4; ++rr) {
        int rowm = 32*w + 16*i + qd*4 + rr;
        float inv = 1.0f / fmaxf(l_run[i][rr], 1e-30f);
        float ov = o[i][c][rr] * inv;
        int e = 16*c + li;
        ob[(((size_t)bb * NS + (q0 + rowm)) * NH + hh) * NE + e] = f2bf(ov);
      }
}

// ---------- output projection; store dtype per flag ----------
__global__ __launch_bounds__(256) void gemm_proj(const unsigned short* __restrict__ A,
                                                 const unsigned short* __restrict__ W2T,
                                                 const unsigned short* __restrict__ bproj,
                                                 void* __restrict__ outv,
                                                 const int* __restrict__ flag) {
  __shared__ unsigned short As[128 * 32];
  __shared__ unsigned short Bs[128 * 32];
  int m0 = blockIdx.y * 128, n0 = blockIdx.x * 128;
  f32x4 acc[4][4] = {};
  gemm_core(A, W2T, ND, m0, n0, As, Bs, acc);
  int isbf = *flag;
  unsigned short* out16 = (unsigned short*)outv;
  float* out32 = (float*)outv;
  int t = threadIdx.x, lane = t & 63, w = t >> 6, wr = w >> 1, wc = w & 1;
  int coln = lane & 15, rbase = (lane >> 4) * 4;
#pragma unroll
  for (int j = 0; j < 4; ++j) {
    int nn = n0 + 64*wc + 16*j + coln;
    float bias = bf2f(bproj[nn]);
#pragma unroll
    for (int i = 0; i < 4; ++i) {
#pragma unroll
      for (int rr = 0; rr < 4; ++rr) {
        int mm = m0 + 64*wr + 16*i + rbase + rr;
        float v = acc[i][j][rr] + bias;
        if (isbf) out16[(size_t)mm * ND + nn] = f2bf(v);
        else      out32[(size_t)mm * ND + nn] = v;
      }
    }
  }
}

extern "C" void kernel_launch(void* const* d_in, const int* in_sizes, int n_in,
                              void* d_out, int out_size, void* d_ws, size_t ws_size,
                              hipStream_t stream) {
  (void)in_sizes; (void)n_in; (void)out_size; (void)ws_size;
  char* ws = (char*)d_ws;
  unsigned short* W1T = (unsigned short*)(ws);                       // 6,291,456
  unsigned short* W2T = (unsigned short*)(ws + 6291456);             // 2,097,152
  unsigned short* qb  = (unsigned short*)(ws + 8388608);             // 16 MB
  unsigned short* kb  = (unsigned short*)(ws + 25165824);            // 16 MB
  unsigned short* vb  = (unsigned short*)(ws + 41943040);            // 16 MB (B,H,E,S)
  unsigned short* ob  = (unsigned short*)(ws + 58720256);            // 16 MB
  unsigned short* bac = (unsigned short*)(ws + 75497472);            // 8 KB
  unsigned short* bpc = (unsigned short*)(ws + 75505664);            // 8 KB
  int*            flg = (int*)(ws + 75513856);
  unsigned short* xc  = ob;   // converted x, dead before ob written

  detect_dtype<<<1, 256, 0, stream>>>((const unsigned*)d_in[0], flg);
  conv_to_bf16<<<2048, 256, 0, stream>>>(d_in[0], xc,  NB*NS*ND, flg);
  conv_to_bf16<<<12,   256, 0, stream>>>(d_in[2], bac, 3*NH*NE, flg);
  conv_to_bf16<<<4,    256, 0, stream>>>(d_in[4], bpc, ND, flg);

  transpose_conv<<<dim3(3072/32, 1024/32), dim3(32, 8), 0, stream>>>(d_in[1], W1T, 1024, 3072, flg);
  transpose_conv<<<dim3(1024/32, 1024/32), dim3(32, 8), 0, stream>>>(d_in[3], W2T, 1024, 1024, flg);
  gemm_qkv256<<<dim3(3072/256, NM/256), 512, 0, stream>>>(xc, W1T, bac, qb, kb, vb);
  attn_causal<<<dim3(1024), 256, 0, stream>>>(qb, kb, vb, ob);
  gemm_proj<<<dim3(1024/128, NM/128), 256, 0, stream>>>(ob, W2T, bpc, d_out, flg);
}

// Round 2
// 305.192 us; speedup vs baseline: 1.0282x; 1.0282x over previous
//
#include <hip/hip_runtime.h>

// Problem: B=4, S=2048, D=1024, H=16, HD=64.
#define NB 4
#define NS 2048
#define ND 1024
#define NH 16
#define NE 64
#define NM (NB*NS)   // 8192 rows

typedef __attribute__((ext_vector_type(8))) __bf16 bf16x8;           // MFMA A/B frag (4 VGPRs)
typedef __attribute__((ext_vector_type(4))) float f32x4;             // MFMA C/D frag

__device__ __forceinline__ float bf2f(unsigned short h) {
  union { unsigned u; float f; } c; c.u = ((unsigned)h) << 16; return c.f;
}
__device__ __forceinline__ unsigned short f2bf(float f) {
  union { float f; unsigned u; } c; c.f = f;
  return (unsigned short)((c.u + 0x7fffu + ((c.u >> 16) & 1u)) >> 16);
}
__device__ __forceinline__ void load16_to_lds(const void* g, void* l) {
  __builtin_amdgcn_global_load_lds(
      (__attribute__((address_space(1))) void*)(void*)(unsigned long long)(const char*)g,
      (__attribute__((address_space(3))) void*)l, 16, 0, 0);
}

// ---------- dtype detection: is d_in data bf16 (1) or fp32 (0)? ----------
__global__ void detect_dtype(const unsigned* __restrict__ x, int* __restrict__ flag) {
  __shared__ int cnt;
  if (threadIdx.x == 0) cnt = 0;
  __syncthreads();
  unsigned w = x[((unsigned)threadIdx.x * 16381u) & ((1u << 21) - 1u)];
  unsigned lo = w & 0xFFFFu;
  int e = (int)((lo >> 7) & 0xFF);
  int plausible = (lo == 0u) || (e >= 100 && e <= 142);
  atomicAdd(&cnt, plausible);
  __syncthreads();
  if (threadIdx.x == 0) *flag = (cnt >= 192) ? 1 : 0;
}

// ---------- canonicalize any input to bf16 ----------
__global__ void conv_to_bf16(const void* __restrict__ src, unsigned short* __restrict__ dst,
                             int n, const int* __restrict__ flag) {
  int stride = gridDim.x * blockDim.x;
  int i0 = blockIdx.x * blockDim.x + threadIdx.x;
  if (*flag) {
    const unsigned short* s = (const unsigned short*)src;
    for (int i = i0; i < n; i += stride) dst[i] = s[i];
  } else {
    const float* s = (const float*)src;
    for (int i = i0; i < n; i += stride) dst[i] = f2bf(s[i]);
  }
}

// ---------- fused convert+transpose: in[K][N] (bf16 or fp32 per flag) -> out[N][K] bf16 ----------
__global__ __launch_bounds__(256) void transpose_conv(const void* __restrict__ in,
                                                      unsigned short* __restrict__ out,
                                                      int K, int N, const int* __restrict__ flag) {
  __shared__ unsigned short tile[32][33];
  int n0 = blockIdx.x * 32, k0 = blockIdx.y * 32;
  int tx = threadIdx.x, ty = threadIdx.y;   // (32,8)
  if (*flag) {
    const unsigned short* p = (const unsigned short*)in;
#pragma unroll
    for (int i = 0; i < 4; ++i)
      tile[ty + 8*i][tx] = p[(size_t)(k0 + ty + 8*i) * N + n0 + tx];
  } else {
    const float* p = (const float*)in;
#pragma unroll
    for (int i = 0; i < 4; ++i)
      tile[ty + 8*i][tx] = f2bf(p[(size_t)(k0 + ty + 8*i) * N + n0 + tx]);
  }
  __syncthreads();
#pragma unroll
  for (int i = 0; i < 4; ++i)
    out[(size_t)(n0 + ty + 8*i) * K + k0 + tx] = tile[tx][ty + 8*i];
}

// ---------- m97-style GEMM core: C[128x128] = A[M,K] * Bt[N,K]^T (kept for gemm_proj) ----------
__device__ __forceinline__ void gemm_core(const unsigned short* __restrict__ A,
                                          const unsigned short* __restrict__ Bt,
                                          int K, int m0, int n0,
                                          unsigned short* As, unsigned short* Bs,
                                          f32x4 (&acc)[4][4]) {
  int t = threadIdx.x;
  int lane = t & 63;
  int w = t >> 6, wr = w >> 1, wc = w & 1;
  int frm = lane & 15, fko = (lane >> 4) * 8;
  for (int kk = 0; kk < K; kk += 32) {
#pragma unroll
    for (int c = 0; c < 2; ++c) {
      int L = c * 256 + t;
      int r = L >> 2, ko = (L & 3) * 8;
      load16_to_lds(A  + (size_t)(m0 + r) * K + kk + ko, (char*)As + L * 16);
      load16_to_lds(Bt + (size_t)(n0 + r) * K + kk + ko, (char*)Bs + L * 16);
    }
    __syncthreads();
    bf16x8 a[4], b[4];
#pragma unroll
    for (int i = 0; i < 4; ++i) a[i] = *(const bf16x8*)(As + (64*wr + 16*i + frm) * 32 + fko);
#pragma unroll
    for (int j = 0; j < 4; ++j) b[j] = *(const bf16x8*)(Bs + (64*wc + 16*j + frm) * 32 + fko);
#pragma unroll
    for (int i = 0; i < 4; ++i)
#pragma unroll
      for (int j = 0; j < 4; ++j)
        acc[i][j] = __builtin_amdgcn_mfma_f32_16x16x32_bf16(a[i], b[j], acc[i][j], 0, 0, 0);
    __syncthreads();
  }
}

// ---------- QKV projection v2: 256x128 tile, 4 waves, 2 blocks/CU, depth-3 ring ----------
// Design: cross-BLOCK overlap instead of intra-block phases. Two independent 4-wave
// blocks co-resident per CU (LDS 72 KiB each, 144 KiB total) desynchronize so one
// block's MFMA covers the other's ds_read/barrier/vmcnt windows (m114 mechanism).
// Per K-tile: {12 ds_read | lgkmcnt(0)+bar (ring-slot t free) | stage t+3 (6 loads) |
// 32 MFMA | vmcnt(12)+bar (tile t+1 landed; 12 loads = tiles t+2,t+3 stay in flight)}.
// Grid 24x32 = 768 blocks at 2/CU -> no idle round (vs 384@1/CU = 25% idle).
// XCD chunk swizzle: 768 = 8 x 96; each XCD owns 4 contiguous m-panels (2 MB X in L2).
#define TSV2 ((256 + 128) * 32)   // elems per ring slot (A 256x32 + B 128x32)

__global__ __launch_bounds__(256, 2) void gemm_qkv_v2(const unsigned short* __restrict__ X,
                                                      const unsigned short* __restrict__ W1T,
                                                      const unsigned short* __restrict__ battn,
                                                      unsigned short* __restrict__ qb,
                                                      unsigned short* __restrict__ kb,
                                                      unsigned short* __restrict__ vb) {
  __shared__ unsigned short sm[3 * TSV2];             // 72 KiB -> 2 blocks/CU
  const int t = threadIdx.x;                          // 0..255
  const int lane = t & 63, w = t >> 6;                // 4 waves
  const int wr = w >> 1, wc = w & 1;                  // wave tile: 128(M) x 64(N)
  const int frm = lane & 15;
  const int gs = (lane >> 4) ^ ((frm >> 1) & 3);      // swizzled K-chunk for ds_read

  // XCD chunk swizzle (bijective: 768 = 8*96): XCD k gets virt in [96k,96k+96)
  // = 4 consecutive m-panels (by) x all 24 n-panels -> X panel reuse in per-XCD L2.
  int flat = blockIdx.x + 24 * blockIdx.y;
  int virt = (flat & 7) * 96 + (flat >> 3);
  const int n0 = (virt % 24) * 128;
  const int m0 = (virt / 24) * 256;
  const int NT = ND / 32;                             // 32 K-tiles

  auto stage_tile = [&](int kt2, int bi2) {
    unsigned short* Ab = sm + bi2 * TSV2;
    unsigned short* Bb = Ab + 256 * 32;
    int kk = kt2 * 32;
#pragma unroll
    for (int u = 0; u < 4; ++u) {                     // A: 256x32 = 1024 chunks
      int ci = u * 256 + t;
      int r = ci >> 2, c = ci & 3;
      int cs = c ^ ((r >> 1) & 3);                    // inverse-swizzled global source
      load16_to_lds(X + (size_t)(m0 + r) * ND + kk + cs * 8, (char*)Ab + ci * 16);
    }
#pragma unroll
    for (int u = 0; u < 2; ++u) {                     // B: 128x32 = 512 chunks
      int ci = u * 256 + t;
      int r = ci >> 2, c = ci & 3;
      int cs = c ^ ((r >> 1) & 3);
      load16_to_lds(W1T + (size_t)(n0 + r) * ND + kk + cs * 8, (char*)Bb + ci * 16);
    }
  };

  // prologue: stage tiles 0,1,2 (18 loads/wave); vmcnt(12) -> tile 0 landed
  stage_tile(0, 0);
  stage_tile(1, 1);
  stage_tile(2, 2);
  asm volatile("s_waitcnt vmcnt(12)\n\ts_barrier" ::: "memory");

  f32x4 acc[8][4] = {};
  for (int kt = 0; kt < NT; ++kt) {
    const unsigned short* Ab = sm + (kt % 3) * TSV2;
    const unsigned short* Bb = Ab + 256 * 32;

    bf16x8 b[4], a[8];
#pragma unroll
    for (int j = 0; j < 4; ++j)
      b[j] = *(const bf16x8*)(Bb + (64*wc + 16*j + frm) * 32 + gs * 8);
#pragma unroll
    for (int i = 0; i < 8; ++i)
      a[i] = *(const bf16x8*)(Ab + (128*wr + 16*i + frm) * 32 + gs * 8);

    if (kt + 3 < NT) {
      // all waves' reads of ring slot (kt%3) complete -> safe to re-stage it
      asm volatile("s_waitcnt lgkmcnt(0)\n\ts_barrier" ::: "memory");
      stage_tile(kt + 3, kt % 3);
    }

    __builtin_amdgcn_s_setprio(1);
#pragma unroll
    for (int i = 0; i < 8; ++i)
#pragma unroll
      for (int j = 0; j < 4; ++j)
        acc[i][j] = __builtin_amdgcn_mfma_f32_16x16x32_bf16(a[i], b[j], acc[i][j], 0, 0, 0);
    __builtin_amdgcn_s_setprio(0);

    // boundary: tile kt+1 must be landed for all waves; keep newer stages in flight
    if (kt + 3 < NT)       asm volatile("s_waitcnt vmcnt(12)\n\ts_barrier" ::: "memory");
    else if (kt == NT - 3) asm volatile("s_waitcnt vmcnt(6)\n\ts_barrier" ::: "memory");
    else if (kt == NT - 2) asm volatile("s_waitcnt vmcnt(0)\n\ts_barrier" ::: "memory");
    // kt == NT-1: fall through to epilogue (register-only)
  }

  // epilogue: scatter q/k:(B,H,S,E), v:(B,H,E,S) — same mapping as verified kernel
  const int coln = frm, rbase = (lane >> 4) * 4;
#pragma unroll
  for (int j = 0; j < 4; ++j) {
    int nn = n0 + 64*wc + 16*j + coln;       // 0..3071
    int qq = nn >> 10;                       // 0=q 1=k 2=v
    int h  = (nn >> 6) & 15;
    int e  = nn & 63;
    float bias = bf2f(battn[nn]);
    unsigned short* dst = (qq == 0) ? qb : ((qq == 1) ? kb : vb);
    float scale = (qq == 0) ? (0.125f * 1.44269504f) : 1.0f;
#pragma unroll
    for (int i = 0; i < 8; ++i) {
#pragma unroll
      for (int rr = 0; rr < 4; ++rr) {
        int mm = m0 + 128*wr + 16*i + rbase + rr;
        int bb = mm >> 11, s = mm & 2047;
        float v = (acc[i][j][rr] + bias) * scale;
        size_t idx;
        if (qq == 2) idx = (((size_t)bb * NH + h) * NE + e) * NS + s;   // V transposed
        else         idx = (((size_t)bb * NH + h) * NS + s) * NE + e;
        dst[idx] = f2bf(v);
      }
    }
  }
}

// ---------- causal flash attention: 1024 fully-resident blocks, 4/CU ----------
// Block i -> (bh = i&63, qt = QTAB[(i>>6)&3][i>>8]); QTAB rows sum to 30 so the 4
// co-resident blocks per CU (i, i+256, ...) balance AND share bh (K/V L2 locality).
// 128 q-rows/block (wave w owns rows 32w..32w+31), 32-key tiles, dbuf DMA, vmcnt(2).
// LDS 32 KB: QPs 16K (Q then P, pitch-64hw octet-swizzled) + K dbuf 8K + V dbuf 8K.
// Vt layout: 32 rows x 128B; row r = e-pair (2r, 2r+1) x 32 keys, octet-swizzled.
__global__ __launch_bounds__(256, 4) void attn_causal(const unsigned short* __restrict__ qb,
                                                      const unsigned short* __restrict__ kb,
                                                      const unsigned short* __restrict__ vtb,
                                                      unsigned short* __restrict__ ob) {
  __shared__ unsigned short QPs[128 * 64];
  __shared__ unsigned short Ks[2][32 * 64];
  __shared__ unsigned short Vt[2][32 * 64];

  int t = threadIdx.x, lane = t & 63, w = t >> 6;
  int qd = lane >> 4, li = lane & 15;
  int sw0 = ((qd ^ (li & 7)) * 8);
  int sw1 = (((4 + qd) ^ (li & 7)) * 8);

  const int qtab[4][4] = {{15,8,7,0},{14,9,6,1},{13,10,5,2},{12,11,4,3}};
  int bi = blockIdx.x;
  int bh = bi & 63;
  int qt = qtab[(bi >> 6) & 3][bi >> 8];
  int q0 = qt * 128;
  int NT = 4 * qt + 4;                       // number of 32-key tiles
  size_t base = (size_t)bh * NS * NE;
  int bb = bh >> 4, hh = bh & 15;

  bf16x8 onesf;
#pragma unroll
  for (int j = 0; j < 8; ++j) onesf[j] = (__bf16)1.0f;

  auto stage_kv = [&](int kt, int buf) {
    int k0 = kt * 32;
    int r = t >> 3, p = t & 7, l = p ^ (r & 7);
    load16_to_lds(kb + base + (size_t)(k0 + r) * NE + l * 8, (char*)Ks[buf] + t * 16);
    int e = 2 * r + (l >> 2);
    load16_to_lds(vtb + base + (size_t)e * NS + k0 + (l & 3) * 8, (char*)Vt[buf] + t * 16);
  };

  // stage Q (128x64, swizzled) + first K/V tile
#pragma unroll
  for (int c = 0; c < 4; ++c) {
    int ch = c * 256 + t;
    int r = ch >> 3, jl = (ch & 7) ^ (r & 7);
    load16_to_lds(qb + base + (size_t)(q0 + r) * NE + jl * 8, (char*)QPs + ch * 16);
  }
  stage_kv(0, 0);
  asm volatile("s_waitcnt vmcnt(2)\n\ts_barrier" ::: "memory");  // Q drained, kv0 in flight

  bf16x8 qa[2][2];
#pragma unroll
  for (int i = 0; i < 2; ++i) {
    const unsigned short* qr = QPs + (32*w + 16*i + li) * 64;
    qa[i][0] = *(const bf16x8*)(qr + sw0);
    qa[i][1] = *(const bf16x8*)(qr + sw1);
  }

  f32x4 o[2][4] = {};
  float l_run[2][4] = {};

  for (int kt = 0; kt < NT; ++kt) {
    int cur = kt & 1;
    // all waves done with buf[cur^1] (and, at kt=0, with their qa reads)
    asm volatile("s_waitcnt lgkmcnt(0)\n\ts_barrier" ::: "memory");
    if (kt + 1 < NT) {
      stage_kv(kt + 1, cur ^ 1);
      asm volatile("s_waitcnt vmcnt(2)\n\ts_barrier" ::: "memory");  // drain tile kt only
    } else {
      asm volatile("s_waitcnt vmcnt(0)\n\ts_barrier" ::: "memory");
    }

    int k0 = kt * 32;
    const unsigned short* Ksc = Ks[cur];
    const unsigned short* Vtc = Vt[cur];

    bf16x8 kfr[2][2];
#pragma unroll
    for (int c = 0; c < 2; ++c) {
      const unsigned short* kr = Ksc + (16*c + li) * 64;
      kfr[c][0] = *(const bf16x8*)(kr + sw0);
      kfr[c][1] = *(const bf16x8*)(kr + sw1);
    }

    int need_mask = (k0 >= q0);
#pragma unroll
    for (int i = 0; i < 2; ++i) {
#pragma unroll
      for (int c = 0; c < 2; ++c) {
        f32x4 s = {};
        s = __builtin_amdgcn_mfma_f32_16x16x32_bf16(qa[i][0], kfr[c][0], s, 0, 0, 0);
        s = __builtin_amdgcn_mfma_f32_16x16x32_bf16(qa[i][1], kfr[c][1], s, 0, 0, 0);
#pragma unroll
        for (int rr = 0; rr < 4; ++rr) {
          float pv = exp2f(s[rr]);
          if (need_mask) {
            int colk = k0 + 16*c + li;
            int rowq = q0 + 32*w + 16*i + qd*4 + rr;
            if (colk > rowq) pv = 0.f;
          }
          int prow = 32*w + 16*i + qd*4 + rr;
          int lo = 2*c + (li >> 3);
          QPs[prow * 64 + ((lo ^ (prow & 7)) * 8) + (li & 7)] =
              (unsigned short)(__float_as_uint(pv) >> 16);
        }
      }
    }

    // read P as A-operand (wave-local rows; in-order LDS => no barrier)
    bf16x8 pa[2];
#pragma unroll
    for (int i = 0; i < 2; ++i)
      pa[i] = *(const bf16x8*)(QPs + (32*w + 16*i + li) * 64 + sw0);

    // row sums via ones-MFMA (k=32 covers the whole tile)
#pragma unroll
    for (int i = 0; i < 2; ++i) {
      f32x4 sm = {};
      sm = __builtin_amdgcn_mfma_f32_16x16x32_bf16(pa[i], onesf, sm, 0, 0, 0);
#pragma unroll
      for (int rr = 0; rr < 4; ++rr) l_run[i][rr] += sm[rr];
    }

    // O += P V : B-frag from packed Vt (row = e>>1, octet = (e&1)*4+qd, swizzled)
#pragma unroll
    for (int c2 = 0; c2 < 4; ++c2) {
      const unsigned short* vr = Vtc + (8*c2 + (li >> 1)) * 64;
      bf16x8 vf = *(const bf16x8*)(vr + ((((li & 1) * 4 + qd) ^ ((li >> 1) & 7)) * 8));
#pragma unroll
      for (int i = 0; i < 2; ++i)
        o[i][c2] = __builtin_amdgcn_mfma_f32_16x16x32_bf16(pa[i], vf, o[i][c2], 0, 0, 0);
    }
  }

  // write O to (B,S,H,E)
#pragma unroll
  for (int i = 0; i < 2; ++i)
#pragma unroll
    for (int c = 0; c < 4; ++c)
#pragma unroll
      for (int rr = 0; rr < 4; ++rr) {
        int rowm = 32*w + 16*i + qd*4 + rr;
        float inv = 1.0f / fmaxf(l_run[i][rr], 1e-30f);
        float ov = o[i][c][rr] * inv;
        int e = 16*c + li;
        ob[(((size_t)bb * NS + (q0 + rowm)) * NH + hh) * NE + e] = f2bf(ov);
      }
}

// ---------- output projection; store dtype per flag ----------
__global__ __launch_bounds__(256) void gemm_proj(const unsigned short* __restrict__ A,
                                                 const unsigned short* __restrict__ W2T,
                                                 const unsigned short* __restrict__ bproj,
                                                 void* __restrict__ outv,
                                                 const int* __restrict__ flag) {
  __shared__ unsigned short As[128 * 32];
  __shared__ unsigned short Bs[128 * 32];
  int m0 = blockIdx.y * 128, n0 = blockIdx.x * 128;
  f32x4 acc[4][4] = {};
  gemm_core(A, W2T, ND, m0, n0, As, Bs, acc);
  int isbf = *flag;
  unsigned short* out16 = (unsigned short*)outv;
  float* out32 = (float*)outv;
  int t = threadIdx.x, lane = t & 63, w = t >> 6, wr = w >> 1, wc = w & 1;
  int coln = lane & 15, rbase = (lane >> 4) * 4;
#pragma unroll
  for (int j = 0; j < 4; ++j) {
    int nn = n0 + 64*wc + 16*j + coln;
    float bias = bf2f(bproj[nn]);
#pragma unroll
    for (int i = 0; i < 4; ++i) {
#pragma unroll
      for (int rr = 0; rr < 4; ++rr) {
        int mm = m0 + 64*wr + 16*i + rbase + rr;
        float v = acc[i][j][rr] + bias;
        if (isbf) out16[(size_t)mm * ND + nn] = f2bf(v);
        else      out32[(size_t)mm * ND + nn] = v;
      }
    }
  }
}

extern "C" void kernel_launch(void* const* d_in, const int* in_sizes, int n_in,
                              void* d_out, int out_size, void* d_ws, size_t ws_size,
                              hipStream_t stream) {
  (void)in_sizes; (void)n_in; (void)out_size; (void)ws_size;
  char* ws = (char*)d_ws;
  unsigned short* W1T = (unsigned short*)(ws);                       // 6,291,456
  unsigned short* W2T = (unsigned short*)(ws + 6291456);             // 2,097,152
  unsigned short* qb  = (unsigned short*)(ws + 8388608);             // 16 MB
  unsigned short* kb  = (unsigned short*)(ws + 25165824);            // 16 MB
  unsigned short* vb  = (unsigned short*)(ws + 41943040);            // 16 MB (B,H,E,S)
  unsigned short* ob  = (unsigned short*)(ws + 58720256);            // 16 MB
  unsigned short* bac = (unsigned short*)(ws + 75497472);            // 8 KB
  unsigned short* bpc = (unsigned short*)(ws + 75505664);            // 8 KB
  int*            flg = (int*)(ws + 75513856);
  unsigned short* xc  = ob;   // converted x, dead before ob written

  detect_dtype<<<1, 256, 0, stream>>>((const unsigned*)d_in[0], flg);
  conv_to_bf16<<<2048, 256, 0, stream>>>(d_in[0], xc,  NB*NS*ND, flg);
  conv_to_bf16<<<12,   256, 0, stream>>>(d_in[2], bac, 3*NH*NE, flg);
  conv_to_bf16<<<4,    256, 0, stream>>>(d_in[4], bpc, ND, flg);

  transpose_conv<<<dim3(3072/32, 1024/32), dim3(32, 8), 0, stream>>>(d_in[1], W1T, 1024, 3072, flg);
  transpose_conv<<<dim3(1024/32, 1024/32), dim3(32, 8), 0, stream>>>(d_in[3], W2T, 1024, 1024, flg);
  gemm_qkv_v2<<<dim3(3072/128, NM/256), 256, 0, stream>>>(xc, W1T, bac, qb, kb, vb);
  attn_causal<<<dim3(1024), 256, 0, stream>>>(qb, kb, vb, ob);
  gemm_proj<<<dim3(1024/128, NM/128), 256, 0, stream>>>(ob, W2T, bpc, d_out, flg);
}

// Round 3
// 288.122 us; speedup vs baseline: 1.0891x; 1.0592x over previous
//
#include <hip/hip_runtime.h>

// Problem: B=4, S=2048, D=1024, H=16, HD=64.
#define NB 4
#define NS 2048
#define ND 1024
#define NH 16
#define NE 64
#define NM (NB*NS)   // 8192 rows

typedef __attribute__((ext_vector_type(8))) __bf16 bf16x8;           // MFMA A/B frag (4 VGPRs)
typedef __attribute__((ext_vector_type(4))) float f32x4;             // MFMA C/D frag

__device__ __forceinline__ float bf2f(unsigned short h) {
  union { unsigned u; float f; } c; c.u = ((unsigned)h) << 16; return c.f;
}
__device__ __forceinline__ unsigned short f2bf(float f) {
  union { float f; unsigned u; } c; c.f = f;
  return (unsigned short)((c.u + 0x7fffu + ((c.u >> 16) & 1u)) >> 16);
}
__device__ __forceinline__ void load16_to_lds(const void* g, void* l) {
  __builtin_amdgcn_global_load_lds(
      (__attribute__((address_space(1))) void*)(void*)(unsigned long long)(const char*)g,
      (__attribute__((address_space(3))) void*)l, 16, 0, 0);
}

// ---------- dtype detection: is d_in data bf16 (1) or fp32 (0)? ----------
__global__ void detect_dtype(const unsigned* __restrict__ x, int* __restrict__ flag) {
  __shared__ int cnt;
  if (threadIdx.x == 0) cnt = 0;
  __syncthreads();
  unsigned w = x[((unsigned)threadIdx.x * 16381u) & ((1u << 21) - 1u)];
  unsigned lo = w & 0xFFFFu;
  int e = (int)((lo >> 7) & 0xFF);
  int plausible = (lo == 0u) || (e >= 100 && e <= 142);
  atomicAdd(&cnt, plausible);
  __syncthreads();
  if (threadIdx.x == 0) *flag = (cnt >= 192) ? 1 : 0;
}

// ---------- canonicalize any input to bf16 ----------
__global__ void conv_to_bf16(const void* __restrict__ src, unsigned short* __restrict__ dst,
                             int n, const int* __restrict__ flag) {
  int stride = gridDim.x * blockDim.x;
  int i0 = blockIdx.x * blockDim.x + threadIdx.x;
  if (*flag) {
    const unsigned short* s = (const unsigned short*)src;
    for (int i = i0; i < n; i += stride) dst[i] = s[i];
  } else {
    const float* s = (const float*)src;
    for (int i = i0; i < n; i += stride) dst[i] = f2bf(s[i]);
  }
}

// ---------- fused convert+transpose: in[K][N] (bf16 or fp32 per flag) -> out[N][K] bf16 ----------
__global__ __launch_bounds__(256) void transpose_conv(const void* __restrict__ in,
                                                      unsigned short* __restrict__ out,
                                                      int K, int N, const int* __restrict__ flag) {
  __shared__ unsigned short tile[32][33];
  int n0 = blockIdx.x * 32, k0 = blockIdx.y * 32;
  int tx = threadIdx.x, ty = threadIdx.y;   // (32,8)
  if (*flag) {
    const unsigned short* p = (const unsigned short*)in;
#pragma unroll
    for (int i = 0; i < 4; ++i)
      tile[ty + 8*i][tx] = p[(size_t)(k0 + ty + 8*i) * N + n0 + tx];
  } else {
    const float* p = (const float*)in;
#pragma unroll
    for (int i = 0; i < 4; ++i)
      tile[ty + 8*i][tx] = f2bf(p[(size_t)(k0 + ty + 8*i) * N + n0 + tx]);
  }
  __syncthreads();
#pragma unroll
  for (int i = 0; i < 4; ++i)
    out[(size_t)(n0 + ty + 8*i) * K + k0 + tx] = tile[tx][ty + 8*i];
}

// ---------- v3 GEMM core: m201-style fine phases ----------
// BM=256, BN=128, BK=64, 8 waves (4M x 2N), wave-tile 64x64, acc[4][4].
// LDS: 3-slot ring, slot = A[256][64] + B[128][64] bf16 = 48 KiB (144 KiB total, 1 blk/CU).
// Per K-tile, 2 fine phases (ks=0, ks=1), each:
//   {8 ds_read_b128 issued | stage part of tile kt+2 | s_barrier | lgkmcnt(0) |
//    setprio(1) 16 MFMA setprio(0) | s_barrier}
// Boundary: vmcnt(6) once per K-tile (tile kt+1's 6 loads are the oldest -> landed;
// kt+2's 6 stay in flight). Drain vmcnt(0) only at kt=NT-2.
// Swizzle (both-sides, rule 21): 128B rows, 8x16B chunks, phys = logical ^ (row&7);
// inverse applied on global source, forward on ds_read offset. 8 lanes per chunk-column
// per b128 -> conflict-free (same family measured 0 conflicts in prior rounds).
#define SLOT_ELEMS ((256 + 128) * 64)

__device__ __forceinline__ void gemm_core_v3(const unsigned short* __restrict__ A,
                                             const unsigned short* __restrict__ Bt,
                                             int m0, int n0,
                                             unsigned short* sm,
                                             f32x4 (&acc)[4][4]) {
  const int t = threadIdx.x;                 // 0..511
  const int lane = t & 63, w = t >> 6;       // 8 waves
  const int wr = w >> 1, wc = w & 1;         // wave tile: 64(M) x 64(N)
  const int frm = lane & 15;
  const int p0 = ((lane >> 4) ^ (frm & 7)) * 8;   // swizzled chunk offset (elems), ks=0

  auto stageA = [&](int kt, int slot) {
    unsigned short* Ab = sm + slot * SLOT_ELEMS;
    int kk = kt * 64;
#pragma unroll
    for (int u = 0; u < 4; ++u) {            // A: 256x64 = 2048 chunks of 16B
      int ci = u * 512 + t;
      int r = ci >> 3, l = (ci & 7) ^ (r & 7);
      load16_to_lds(A + (size_t)(m0 + r) * ND + kk + l * 8, (char*)Ab + ci * 16);
    }
  };
  auto stageB = [&](int kt, int slot) {
    unsigned short* Bb = sm + slot * SLOT_ELEMS + 256 * 64;
    int kk = kt * 64;
#pragma unroll
    for (int u = 0; u < 2; ++u) {            // B: 128x64 = 1024 chunks of 16B
      int ci = u * 512 + t;
      int r = ci >> 3, l = (ci & 7) ^ (r & 7);
      load16_to_lds(Bt + (size_t)(n0 + r) * ND + kk + l * 8, (char*)Bb + ci * 16);
    }
  };

  // prologue: stage tiles 0,1 (12 loads/thread); vmcnt(6) -> tile 0 fully landed
  stageA(0, 0); stageB(0, 0);
  stageA(1, 1); stageB(1, 1);
  asm volatile("s_waitcnt vmcnt(6)\n\ts_barrier" ::: "memory");

  const int NT = ND / 64;                    // 16 K-tiles
  for (int kt = 0; kt < NT; ++kt) {
    const unsigned short* Ab = sm + (kt % 3) * SLOT_ELEMS;
    const unsigned short* Bb = Ab + 256 * 64;
    const int ss = (kt + 2) % 3;
    const bool st = (kt + 2 < NT);

    bf16x8 a[4], b[4];
    // ---- phase 0 (ks=0): reads issued, stage A(kt+2), barrier absorbs ds latency ----
#pragma unroll
    for (int i = 0; i < 4; ++i)
      a[i] = *(const bf16x8*)(Ab + (64*wr + 16*i + frm) * 64 + p0);
#pragma unroll
    for (int j = 0; j < 4; ++j)
      b[j] = *(const bf16x8*)(Bb + (64*wc + 16*j + frm) * 64 + p0);
    if (st) stageA(kt + 2, ss);
    asm volatile("s_barrier" ::: "memory");
    asm volatile("s_waitcnt lgkmcnt(0)" ::: "memory");
    __builtin_amdgcn_s_setprio(1);
#pragma unroll
    for (int i = 0; i < 4; ++i)
#pragma unroll
      for (int j = 0; j < 4; ++j)
        acc[i][j] = __builtin_amdgcn_mfma_f32_16x16x32_bf16(a[i], b[j], acc[i][j], 0, 0, 0);
    __builtin_amdgcn_s_setprio(0);
    asm volatile("s_barrier" ::: "memory");

    // ---- phase 1 (ks=1): reads issued, stage B(kt+2) ----
#pragma unroll
    for (int i = 0; i < 4; ++i)
      a[i] = *(const bf16x8*)(Ab + (64*wr + 16*i + frm) * 64 + (p0 ^ 32));
#pragma unroll
    for (int j = 0; j < 4; ++j)
      b[j] = *(const bf16x8*)(Bb + (64*wc + 16*j + frm) * 64 + (p0 ^ 32));
    if (st) stageB(kt + 2, ss);
    asm volatile("s_barrier" ::: "memory");
    asm volatile("s_waitcnt lgkmcnt(0)" ::: "memory");
    __builtin_amdgcn_s_setprio(1);
#pragma unroll
    for (int i = 0; i < 4; ++i)
#pragma unroll
      for (int j = 0; j < 4; ++j)
        acc[i][j] = __builtin_amdgcn_mfma_f32_16x16x32_bf16(a[i], b[j], acc[i][j], 0, 0, 0);
    __builtin_amdgcn_s_setprio(0);

    // K-tile boundary: tile kt+1 (6 oldest loads) landed; tile kt+2 stays in flight
    if (kt < NT - 2)       asm volatile("s_waitcnt vmcnt(6)\n\ts_barrier" ::: "memory");
    else if (kt == NT - 2) asm volatile("s_waitcnt vmcnt(0)\n\ts_barrier" ::: "memory");
    // kt == NT-1: fall through to epilogue (register-only)
  }
}

// ---------- QKV projection, v3 core; scatter q/k:(B,H,S,E), v:(B,H,E,S) ----------
__global__ __launch_bounds__(512, 1) void gemm_qkv_v3(const unsigned short* __restrict__ X,
                                                      const unsigned short* __restrict__ W1T,
                                                      const unsigned short* __restrict__ battn,
                                                      unsigned short* __restrict__ qb,
                                                      unsigned short* __restrict__ kb,
                                                      unsigned short* __restrict__ vb) {
  __shared__ unsigned short sm[3 * SLOT_ELEMS];      // 144 KiB
  // XCD bijective swizzle: 768 = 8*96; XCD k owns 4 consecutive m-panels x all n-panels.
  int flat = blockIdx.x + 24 * blockIdx.y;
  int virt = (flat & 7) * 96 + (flat >> 3);
  const int n0 = (virt % 24) * 128;
  const int m0 = (virt / 24) * 256;

  f32x4 acc[4][4] = {};
  gemm_core_v3(X, W1T, m0, n0, sm, acc);

  const int t = threadIdx.x, lane = t & 63, w = t >> 6;
  const int wr = w >> 1, wc = w & 1;
  const int coln = lane & 15, rbase = (lane >> 4) * 4;
#pragma unroll
  for (int j = 0; j < 4; ++j) {
    int nn = n0 + 64*wc + 16*j + coln;       // 0..3071
    int qq = nn >> 10;                       // 0=q 1=k 2=v
    int h  = (nn >> 6) & 15;
    int e  = nn & 63;
    float bias = bf2f(battn[nn]);
    unsigned short* dst = (qq == 0) ? qb : ((qq == 1) ? kb : vb);
    float scale = (qq == 0) ? (0.125f * 1.44269504f) : 1.0f;
#pragma unroll
    for (int i = 0; i < 4; ++i) {
#pragma unroll
      for (int rr = 0; rr < 4; ++rr) {
        int mm = m0 + 64*wr + 16*i + rbase + rr;
        int bb = mm >> 11, s = mm & 2047;
        float v = (acc[i][j][rr] + bias) * scale;
        size_t idx;
        if (qq == 2) idx = (((size_t)bb * NH + h) * NE + e) * NS + s;   // V transposed
        else         idx = (((size_t)bb * NH + h) * NS + s) * NE + e;
        dst[idx] = f2bf(v);
      }
    }
  }
}

// ---------- output projection, v3 core; store dtype per flag ----------
__global__ __launch_bounds__(512, 1) void gemm_proj_v3(const unsigned short* __restrict__ A,
                                                       const unsigned short* __restrict__ W2T,
                                                       const unsigned short* __restrict__ bproj,
                                                       void* __restrict__ outv,
                                                       const int* __restrict__ flag) {
  __shared__ unsigned short sm[3 * SLOT_ELEMS];      // 144 KiB
  // 256 blocks = exactly 1/CU; XCD swizzle: 256 = 8*32 (A-panel reuse within XCD).
  int flat = blockIdx.x + 8 * blockIdx.y;
  int virt = (flat & 7) * 32 + (flat >> 3);
  const int n0 = (virt % 8) * 128;
  const int m0 = (virt / 8) * 256;

  f32x4 acc[4][4] = {};
  gemm_core_v3(A, W2T, m0, n0, sm, acc);

  const int isbf = *flag;
  unsigned short* out16 = (unsigned short*)outv;
  float* out32 = (float*)outv;
  const int t = threadIdx.x, lane = t & 63, w = t >> 6;
  const int wr = w >> 1, wc = w & 1;
  const int coln = lane & 15, rbase = (lane >> 4) * 4;
#pragma unroll
  for (int j = 0; j < 4; ++j) {
    int nn = n0 + 64*wc + 16*j + coln;
    float bias = bf2f(bproj[nn]);
#pragma unroll
    for (int i = 0; i < 4; ++i) {
#pragma unroll
      for (int rr = 0; rr < 4; ++rr) {
        int mm = m0 + 64*wr + 16*i + rbase + rr;
        float v = acc[i][j][rr] + bias;
        if (isbf) out16[(size_t)mm * ND + nn] = f2bf(v);
        else      out32[(size_t)mm * ND + nn] = v;
      }
    }
  }
}

// ---------- causal flash attention: 1024 fully-resident blocks, 4/CU ----------
// Block i -> (bh = i&63, qt = QTAB[(i>>6)&3][i>>8]); QTAB rows sum to 30 so the 4
// co-resident blocks per CU (i, i+256, ...) balance AND share bh (K/V L2 locality).
// 128 q-rows/block (wave w owns rows 32w..32w+31), 32-key tiles, dbuf DMA, vmcnt(2).
// LDS 32 KB: QPs 16K (Q then P, pitch-64hw octet-swizzled) + K dbuf 8K + V dbuf 8K.
// Vt layout: 32 rows x 128B; row r = e-pair (2r, 2r+1) x 32 keys, octet-swizzled.
__global__ __launch_bounds__(256, 4) void attn_causal(const unsigned short* __restrict__ qb,
                                                      const unsigned short* __restrict__ kb,
                                                      const unsigned short* __restrict__ vtb,
                                                      unsigned short* __restrict__ ob) {
  __shared__ unsigned short QPs[128 * 64];
  __shared__ unsigned short Ks[2][32 * 64];
  __shared__ unsigned short Vt[2][32 * 64];

  int t = threadIdx.x, lane = t & 63, w = t >> 6;
  int qd = lane >> 4, li = lane & 15;
  int sw0 = ((qd ^ (li & 7)) * 8);
  int sw1 = (((4 + qd) ^ (li & 7)) * 8);

  const int qtab[4][4] = {{15,8,7,0},{14,9,6,1},{13,10,5,2},{12,11,4,3}};
  int bi = blockIdx.x;
  int bh = bi & 63;
  int qt = qtab[(bi >> 6) & 3][bi >> 8];
  int q0 = qt * 128;
  int NT = 4 * qt + 4;                       // number of 32-key tiles
  size_t base = (size_t)bh * NS * NE;
  int bb = bh >> 4, hh = bh & 15;

  bf16x8 onesf;
#pragma unroll
  for (int j = 0; j < 8; ++j) onesf[j] = (__bf16)1.0f;

  auto stage_kv = [&](int kt, int buf) {
    int k0 = kt * 32;
    int r = t >> 3, p = t & 7, l = p ^ (r & 7);
    load16_to_lds(kb + base + (size_t)(k0 + r) * NE + l * 8, (char*)Ks[buf] + t * 16);
    int e = 2 * r + (l >> 2);
    load16_to_lds(vtb + base + (size_t)e * NS + k0 + (l & 3) * 8, (char*)Vt[buf] + t * 16);
  };

  // stage Q (128x64, swizzled) + first K/V tile
#pragma unroll
  for (int c = 0; c < 4; ++c) {
    int ch = c * 256 + t;
    int r = ch >> 3, jl = (ch & 7) ^ (r & 7);
    load16_to_lds(qb + base + (size_t)(q0 + r) * NE + jl * 8, (char*)QPs + ch * 16);
  }
  stage_kv(0, 0);
  asm volatile("s_waitcnt vmcnt(2)\n\ts_barrier" ::: "memory");  // Q drained, kv0 in flight

  bf16x8 qa[2][2];
#pragma unroll
  for (int i = 0; i < 2; ++i) {
    const unsigned short* qr = QPs + (32*w + 16*i + li) * 64;
    qa[i][0] = *(const bf16x8*)(qr + sw0);
    qa[i][1] = *(const bf16x8*)(qr + sw1);
  }

  f32x4 o[2][4] = {};
  float l_run[2][4] = {};

  for (int kt = 0; kt < NT; ++kt) {
    int cur = kt & 1;
    // all waves done with buf[cur^1] (and, at kt=0, with their qa reads)
    asm volatile("s_waitcnt lgkmcnt(0)\n\ts_barrier" ::: "memory");
    if (kt + 1 < NT) {
      stage_kv(kt + 1, cur ^ 1);
      asm volatile("s_waitcnt vmcnt(2)\n\ts_barrier" ::: "memory");  // drain tile kt only
    } else {
      asm volatile("s_waitcnt vmcnt(0)\n\ts_barrier" ::: "memory");
    }

    int k0 = kt * 32;
    const unsigned short* Ksc = Ks[cur];
    const unsigned short* Vtc = Vt[cur];

    bf16x8 kfr[2][2];
#pragma unroll
    for (int c = 0; c < 2; ++c) {
      const unsigned short* kr = Ksc + (16*c + li) * 64;
      kfr[c][0] = *(const bf16x8*)(kr + sw0);
      kfr[c][1] = *(const bf16x8*)(kr + sw1);
    }

    int need_mask = (k0 >= q0);
#pragma unroll
    for (int i = 0; i < 2; ++i) {
#pragma unroll
      for (int c = 0; c < 2; ++c) {
        f32x4 s = {};
        s = __builtin_amdgcn_mfma_f32_16x16x32_bf16(qa[i][0], kfr[c][0], s, 0, 0, 0);
        s = __builtin_amdgcn_mfma_f32_16x16x32_bf16(qa[i][1], kfr[c][1], s, 0, 0, 0);
#pragma unroll
        for (int rr = 0; rr < 4; ++rr) {
          float pv = exp2f(s[rr]);
          if (need_mask) {
            int colk = k0 + 16*c + li;
            int rowq = q0 + 32*w + 16*i + qd*4 + rr;
            if (colk > rowq) pv = 0.f;
          }
          int prow = 32*w + 16*i + qd*4 + rr;
          int lo = 2*c + (li >> 3);
          QPs[prow * 64 + ((lo ^ (prow & 7)) * 8) + (li & 7)] =
              (unsigned short)(__float_as_uint(pv) >> 16);
        }
      }
    }

    // read P as A-operand (wave-local rows; in-order LDS => no barrier)
    bf16x8 pa[2];
#pragma unroll
    for (int i = 0; i < 2; ++i)
      pa[i] = *(const bf16x8*)(QPs + (32*w + 16*i + li) * 64 + sw0);

    // row sums via ones-MFMA (k=32 covers the whole tile)
#pragma unroll
    for (int i = 0; i < 2; ++i) {
      f32x4 sm = {};
      sm = __builtin_amdgcn_mfma_f32_16x16x32_bf16(pa[i], onesf, sm, 0, 0, 0);
#pragma unroll
      for (int rr = 0; rr < 4; ++rr) l_run[i][rr] += sm[rr];
    }

    // O += P V : B-frag from packed Vt (row = e>>1, octet = (e&1)*4+qd, swizzled)
#pragma unroll
    for (int c2 = 0; c2 < 4; ++c2) {
      const unsigned short* vr = Vtc + (8*c2 + (li >> 1)) * 64;
      bf16x8 vf = *(const bf16x8*)(vr + ((((li & 1) * 4 + qd) ^ ((li >> 1) & 7)) * 8));
#pragma unroll
      for (int i = 0; i < 2; ++i)
        o[i][c2] = __builtin_amdgcn_mfma_f32_16x16x32_bf16(pa[i], vf, o[i][c2], 0, 0, 0);
    }
  }

  // write O to (B,S,H,E)
#pragma unroll
  for (int i = 0; i < 2; ++i)
#pragma unroll
    for (int c = 0; c < 4; ++c)
#pragma unroll
      for (int rr = 0; rr < 4; ++rr) {
        int rowm = 32*w + 16*i + qd*4 + rr;
        float inv = 1.0f / fmaxf(l_run[i][rr], 1e-30f);
        float ov = o[i][c][rr] * inv;
        int e = 16*c + li;
        ob[(((size_t)bb * NS + (q0 + rowm)) * NH + hh) * NE + e] = f2bf(ov);
      }
}

extern "C" void kernel_launch(void* const* d_in, const int* in_sizes, int n_in,
                              void* d_out, int out_size, void* d_ws, size_t ws_size,
                              hipStream_t stream) {
  (void)in_sizes; (void)n_in; (void)out_size; (void)ws_size;
  char* ws = (char*)d_ws;
  unsigned short* W1T = (unsigned short*)(ws);                       // 6,291,456
  unsigned short* W2T = (unsigned short*)(ws + 6291456);             // 2,097,152
  unsigned short* qb  = (unsigned short*)(ws + 8388608);             // 16 MB
  unsigned short* kb  = (unsigned short*)(ws + 25165824);            // 16 MB
  unsigned short* vb  = (unsigned short*)(ws + 41943040);            // 16 MB (B,H,E,S)
  unsigned short* ob  = (unsigned short*)(ws + 58720256);            // 16 MB
  unsigned short* bac = (unsigned short*)(ws + 75497472);            // 8 KB
  unsigned short* bpc = (unsigned short*)(ws + 75505664);            // 8 KB
  int*            flg = (int*)(ws + 75513856);
  unsigned short* xc  = ob;   // converted x, dead before ob written

  detect_dtype<<<1, 256, 0, stream>>>((const unsigned*)d_in[0], flg);
  conv_to_bf16<<<2048, 256, 0, stream>>>(d_in[0], xc,  NB*NS*ND, flg);
  conv_to_bf16<<<12,   256, 0, stream>>>(d_in[2], bac, 3*NH*NE, flg);
  conv_to_bf16<<<4,    256, 0, stream>>>(d_in[4], bpc, ND, flg);

  transpose_conv<<<dim3(3072/32, 1024/32), dim3(32, 8), 0, stream>>>(d_in[1], W1T, 1024, 3072, flg);
  transpose_conv<<<dim3(1024/32, 1024/32), dim3(32, 8), 0, stream>>>(d_in[3], W2T, 1024, 1024, flg);
  gemm_qkv_v3<<<dim3(3072/128, NM/256), 512, 0, stream>>>(xc, W1T, bac, qb, kb, vb);
  attn_causal<<<dim3(1024), 256, 0, stream>>>(qb, kb, vb, ob);
  gemm_proj_v3<<<dim3(1024/128, NM/256), 512, 0, stream>>>(ob, W2T, bpc, d_out, flg);
}